// Round 15
// baseline (1571.936 us; speedup 1.0000x reference)
//
#include <hip/hip_runtime.h>
#include <math.h>

#define VOCAB 20000
#define WORD 620
#define NSEQ 128
#define TMAX 30
#define CTXK 2400
#define XK 3020
#define NBLK 256

typedef unsigned long long u64;
typedef __attribute__((ext_vector_type(8))) short short8;
typedef __attribute__((ext_vector_type(4))) float f32x4;

// ---------- helpers ----------
__device__ __forceinline__ unsigned ford(float f) {
    unsigned b = __float_as_uint(f);
    return (b & 0x80000000u) ? ~b : (b | 0x80000000u);
}
__device__ __forceinline__ unsigned short bf16rne(float x) {
    unsigned u = __float_as_uint(x);
    return (unsigned short)((u + 0x7fffu + ((u >> 16) & 1u)) >> 16);
}
__device__ __forceinline__ float bf16tof(unsigned short h) {
    return __uint_as_float(((unsigned)h) << 16);
}
__device__ __forceinline__ short8 ld8(const unsigned short* p) {
    return *(const short8*)p;
}
#define MFMA(a, b, c) __builtin_amdgcn_mfma_f32_16x16x32_bf16((a), (b), (c), 0, 0, 0)
#define VMW(N) asm volatile("s_waitcnt vmcnt(" #N ")" ::: "memory")
#define AL64(p) __hip_atomic_load((p), __ATOMIC_RELAXED, __HIP_MEMORY_SCOPE_AGENT)
#define AADD(p) __hip_atomic_fetch_add((p), 1u, __ATOMIC_RELAXED, __HIP_MEMORY_SCOPE_AGENT)
#define ALD(p) __hip_atomic_load((p), __ATOMIC_RELAXED, __HIP_MEMORY_SCOPE_AGENT)

// async 16B/lane global->LDS copy; LDS dest = uniform base + lane*16
__device__ __forceinline__ void gload_lds16(const void* g, void* l) {
    __builtin_amdgcn_global_load_lds((const __attribute__((address_space(1))) void*)g,
                                     (__attribute__((address_space(3))) void*)l,
                                     16, 0, 0);
}

// =====================================================================
// Shared fragment layout (m91-verified trio), all buffers [tile][ks][2][64][8]:
//   A frag: lane holds A[row = mt*16 + lane%16][k = ks*32 + (lane/16)*8 + j]
//   B frag: lane holds B[col = vt*16 + lane%16][k = ...same...]
//   C/D:    row = (lane>>4)*4 + r, col = lane&15
// =====================================================================

__global__ __launch_bounds__(256) void kpack_w(const float* __restrict__ src,
                                               unsigned short* __restrict__ dst,
                                               int nvt, int nks, int col0,
                                               int ncols_valid, int src_ld,
                                               int nrows_valid, int rowmap) {
    int i = blockIdx.x * 256 + threadIdx.x;
    if (i >= nvt * nks * 512) return;
    int j = i & 7;
    int lane = (i >> 3) & 63;
    int t2 = i >> 9;
    int ks = t2 % nks;
    int vt = t2 / nks;
    int r = vt * 16 + (lane & 15);
    int k = ks * 32 + ((lane >> 4) << 3) + j;
    float x = 0.f;
    if (r < nrows_valid && k < ncols_valid) {
        int row = (rowmap == 1) ? ((r < 620) ? r : r + 620) : r;
        x = src[(size_t)row * src_ld + col0 + k];
    }
    unsigned short hi = bf16rne(x);
    unsigned short lo = bf16rne(x - bf16tof(hi));
    size_t ob = (size_t)t2 * 1024 + lane * 8 + j;
    dst[ob] = hi;
    dst[ob + 512] = lo;
}

__global__ __launch_bounds__(256) void kpack_ctx(const float* __restrict__ th,
                                                 unsigned short* __restrict__ dst) {
    int i = blockIdx.x * 256 + threadIdx.x;
    if (i >= 75 * 8 * 512) return;
    int j = i & 7;
    int lane = (i >> 3) & 63;
    int t2 = i >> 9;
    int mt = t2 & 7;
    int ks = t2 >> 3;
    int n = mt * 16 + (lane & 15);
    int k = ks * 32 + ((lane >> 4) << 3) + j;
    float x = (k < 1200) ? th[(size_t)n * 1200 + k]
                         : th[(size_t)(n + 2) * 1200 + (k - 1200)];
    unsigned short hi = bf16rne(x);
    unsigned short lo = bf16rne(x - bf16tof(hi));
    size_t ob = (size_t)t2 * 1024 + lane * 8 + j;
    dst[ob] = hi;
    dst[ob + 512] = lo;
}

__global__ __launch_bounds__(256) void kpack_embed(const float* __restrict__ embed,
                                                   unsigned short* __restrict__ ehi,
                                                   unsigned short* __restrict__ elo) {
    size_t i = (size_t)blockIdx.x * 256 + threadIdx.x;
    if (i >= (size_t)VOCAB * 640) return;
    int v = (int)(i / 640);
    int k = (int)(i % 640);
    float x = (k < WORD) ? embed[(size_t)v * WORD + k] : 0.f;
    unsigned short hi = bf16rne(x);
    ehi[i] = hi;
    elo[i] = bf16rne(x - bf16tof(hi));
}

// generic frag GEMM (setup only): outT[row][col] = A@B^T (+addRow)
__global__ __launch_bounds__(256) void ggemm(const unsigned short* __restrict__ Af,
                                             const unsigned short* __restrict__ Bf,
                                             const float* __restrict__ addRow,
                                             const float* __restrict__ addFull,
                                             float* __restrict__ outT,
                                             int nks, int nvt, int ldout) {
    int lane = threadIdx.x & 63, wv = threadIdx.x >> 6;
    int vtb = blockIdx.x * 8 + wv * 2;
    bool ok0 = vtb < nvt, ok1 = (vtb + 1) < nvt;
    f32x4 acc[8][2];
#pragma unroll
    for (int m = 0; m < 8; ++m) { acc[m][0] = (f32x4)0.f; acc[m][1] = (f32x4)0.f; }
    if (ok0) {
        const unsigned short* ap = Af + lane * 8;
        const unsigned short* bp0 = Bf + (size_t)vtb * nks * 1024 + lane * 8;
        const unsigned short* bp1 = bp0 + (size_t)nks * 1024;
        for (int ks = 0; ks < nks; ++ks) {
            short8 b0h = ld8(bp0), b0l = ld8(bp0 + 512);
            short8 ah[8], al[8];
#pragma unroll
            for (int m = 0; m < 8; ++m) {
                ah[m] = ld8(ap + m * 1024);
                al[m] = ld8(ap + m * 1024 + 512);
            }
#pragma unroll
            for (int m = 0; m < 8; ++m) {
                acc[m][0] = MFMA(ah[m], b0h, acc[m][0]);
                acc[m][0] = MFMA(ah[m], b0l, acc[m][0]);
                acc[m][0] = MFMA(al[m], b0h, acc[m][0]);
            }
            if (ok1) {
                short8 b1h = ld8(bp1), b1l = ld8(bp1 + 512);
#pragma unroll
                for (int m = 0; m < 8; ++m) {
                    acc[m][1] = MFMA(ah[m], b1h, acc[m][1]);
                    acc[m][1] = MFMA(ah[m], b1l, acc[m][1]);
                    acc[m][1] = MFMA(al[m], b1h, acc[m][1]);
                }
            }
            ap += 8192; bp0 += 1024; bp1 += 1024;
        }
    }
    int rbase = (lane >> 4) << 2;
    int cof = lane & 15;
#pragma unroll
    for (int v = 0; v < 2; ++v) {
        bool ok = v ? ok1 : ok0;
        if (!ok) continue;
        int col = (vtb + v) * 16 + cof;
        float ar = addRow ? addRow[col] : 0.f;
#pragma unroll
        for (int m = 0; m < 8; ++m) {
#pragma unroll
            for (int r = 0; r < 4; ++r) {
                int row = m * 16 + rbase + r;
                float x = acc[m][v][r] + ar;
                if (addFull) x += addFull[(size_t)row * ldout + col];
                outT[(size_t)row * ldout + col] = x;
            }
        }
    }
}

// init for mega path
__global__ __launch_bounds__(256) void kinit3(unsigned* hf32, unsigned* slots32,
                                              float* bsum, unsigned* bar,
                                              const float* __restrict__ b_ih,
                                              const float* __restrict__ b_hh) {
    int i = blockIdx.x * 256 + threadIdx.x;
    if (i < 81920) hf32[i] = 0u;
    if (i < 7680) slots32[i] = 0u;
    if (i < 512) bar[i] = 0u;
    if (i < 1872) {
        float v = 0.f;
        if (i < 1860) {
            int row = (i < 620) ? i : i + 620;   // [i, g, o] -> W_ih rows
            v = b_ih[row] + b_hh[row];
        }
        bsum[i] = v;
    }
}

// =====================================================================
// Persistent decode kernel v12 = round-14 math/pipeline (bit-identical) +
// critical-path surgery:
//  - bar2 (slots ready, all 256 arrive, 16 spread lines + root at bar[256])
//    is WAITED ON ONLY by the 39 G-blocks;
//  - flag1 (hf ready) is ARRIVED AT ONLY by G-blocks (5 spread lines at
//    bar[272+g*16], root bar[352], 5 arrivals/step), waited on by all;
//  - out stores moved AFTER the bar2 arrival -> overlap with G(t+1) and
//    other blocks' waits.
// =====================================================================
__global__ __launch_bounds__(512, 2) void kmega(
    const unsigned short* __restrict__ embhi,
    const unsigned short* __restrict__ emblo,
    const unsigned short* __restrict__ Wgf3,
    const unsigned short* __restrict__ Wwf,
    const float* __restrict__ base,
    const float* __restrict__ bw,
    unsigned short* __restrict__ hf,
    u64* __restrict__ slots,
    float* __restrict__ out,
    unsigned* bar) {
    __shared__ char sBhi[102400];              // [vt_local][ks][1024B]
    __shared__ char sA[3][16384];
    __shared__ u64 keybuf[128];
    const int tid = threadIdx.x;
    const int lane = tid & 63;
    const int wv = tid >> 6;                   // 0..7
    const int bid = blockIdx.x;

    const int vt_lo = (int)(((long long)bid * 1250) / NBLK);
    const int vt_hi = (int)(((long long)(bid + 1) * 1250) / NBLK);
    const int nvt = vt_hi - vt_lo;             // 4 or 5
    const bool act = (wv < nvt);               // wave owns one vt
    const int myvt = vt_lo + (act ? wv : 0);
    const bool gact = (bid < 39);              // block owns G-vt = bid, wave = mt

    const char* hfb = (const char*)hf;
    const char* wwb = (const char*)Wwf;
    const unsigned short* BbaseLo = Wwf + (size_t)myvt * 20480 + 512 + lane * 8;

    // ---- one-time: stage B-hi (nvt*20 lines of 1 KB) into LDS ----
    for (int i = wv; i < nvt * 20; i += 8) {
        const char* g = wwb + (size_t)(vt_lo + i / 20) * 40960 + (size_t)(i % 20) * 2048 + lane * 16;
        gload_lds16(g, sBhi + (size_t)i * 1024);
    }
    VMW(0);
    __syncthreads();

    u64 R[3][4];
    short8 Bl[4];

#define ISSUE(M)                                                               \
    do {                                                                       \
        const u64* ga_ = (const u64*)(hfb + (size_t)(M) * 16384 +              \
                                      wv * 2048 + lane * 16);                  \
        R[(M) % 3][0] = AL64(ga_ + 0);                                         \
        R[(M) % 3][1] = AL64(ga_ + 1);                                         \
        R[(M) % 3][2] = AL64(ga_ + 128);                                       \
        R[(M) % 3][3] = AL64(ga_ + 129);                                       \
        if (act) Bl[(M) % 4] = ld8(BbaseLo + (size_t)(M) * 1024);              \
    } while (0)

#define WRA(M)                                                                 \
    do {                                                                       \
        u64* da_ = (u64*)(sA[(M) % 3] + wv * 2048 + lane * 16);                \
        da_[0] = R[(M) % 3][0];                                                \
        da_[1] = R[(M) % 3][1];                                                \
        da_[128] = R[(M) % 3][2];                                              \
        da_[129] = R[(M) % 3][3];                                              \
    } while (0)

// per-chunk per-wave vmem ops: act ? 5 : 4 (4 A atomics + 1 B-lo load)
#define LSTEP(K)                                                               \
    do {                                                                       \
        if ((K) + 3 < 20) ISSUE((K) + 3);                                      \
        if ((K) <= 16) { if (act) { VMW(10); } else { VMW(8); } }              \
        else if ((K) == 17) { if (act) { VMW(5); } else { VMW(4); } }          \
        else { VMW(0); }                                                       \
        if ((K) + 1 < 20) WRA((K) + 1);                                        \
        asm volatile("s_waitcnt lgkmcnt(0)" ::: "memory");                     \
        __builtin_amdgcn_s_barrier();                                          \
        __builtin_amdgcn_sched_barrier(0);                                     \
        if (act) {                                                             \
            const unsigned short* ab_ = (const unsigned short*)sA[(K) % 3];    \
            short8 bh_ = ld8((const unsigned short*)(sBhi +                    \
                             (size_t)(wv * 20 + (K)) * 1024) + lane * 8);      \
            _Pragma("unroll")                                                  \
            for (int mt = 0; mt < 8; ++mt) {                                   \
                short8 ah_ = ld8(ab_ + mt * 1024 + lane * 8);                  \
                short8 al_ = ld8(ab_ + mt * 1024 + 512 + lane * 8);            \
                acc[mt] = MFMA(ah_, bh_, acc[mt]);                             \
                acc[mt] = MFMA(ah_, Bl[(K) % 4], acc[mt]);                     \
                acc[mt] = MFMA(al_, bh_, acc[mt]);                             \
            }                                                                  \
        }                                                                      \
    } while (0)

    for (int t = 0; t < TMAX; ++t) {
        // ---------- G: gates + activation -> hf (G-blocks only) ----------
        if (gact) {
            if (t > 0) {
                // wait bar2: all blocks contributed slots[t-1]
                if (tid == 0)
                    while (ALD(&bar[256]) < 16u * (unsigned)t)
                        __builtin_amdgcn_s_sleep(2);
                __syncthreads();
            }
            const int g_vt = bid;              // 0..38
            const int g_mt = wv;               // 0..7
            f32x4 aI = (f32x4)0.f, aG = (f32x4)0.f, aO = (f32x4)0.f;
            if (t > 0) {
                int n = g_mt * 16 + (lane & 15);
                u64 s = AL64(&slots[(size_t)(t - 1) * NSEQ + n]);
                unsigned idx = 0xFFFFFFFFu - (unsigned)(s & 0xFFFFFFFFull);
                const unsigned short* eh = embhi + (size_t)idx * 640 + ((lane >> 4) << 3);
                const unsigned short* el = emblo + (size_t)idx * 640 + ((lane >> 4) << 3);
                const unsigned short* bI = Wgf3 + (size_t)(0 * 39 + g_vt) * 20480 + lane * 8;
                const unsigned short* bG = Wgf3 + (size_t)(1 * 39 + g_vt) * 20480 + lane * 8;
                const unsigned short* bO = Wgf3 + (size_t)(2 * 39 + g_vt) * 20480 + lane * 8;
#pragma unroll 2
                for (int ks = 0; ks < 20; ++ks) {
                    short8 ah = ld8(eh + ks * 32);
                    short8 al = ld8(el + ks * 32);
                    short8 bIh = ld8(bI), bIl = ld8(bI + 512);
                    short8 bGh = ld8(bG), bGl = ld8(bG + 512);
                    short8 bOh = ld8(bO), bOl = ld8(bO + 512);
                    aI = MFMA(ah, bIh, aI); aI = MFMA(ah, bIl, aI); aI = MFMA(al, bIh, aI);
                    aG = MFMA(ah, bGh, aG); aG = MFMA(ah, bGl, aG); aG = MFMA(al, bGh, aG);
                    aO = MFMA(ah, bOh, aO); aO = MFMA(ah, bOl, aO); aO = MFMA(al, bOh, aO);
                    bI += 1024; bG += 1024; bO += 1024;
                }
            }
            int col = g_vt * 16 + (lane & 15);
            if (col < WORD) {
                int rbase = g_mt * 16 + ((lane >> 4) << 2);
#pragma unroll
                for (int r = 0; r < 4; ++r) {
                    int n = rbase + r;
                    float gi = aI[r] + base[(size_t)n * 1872 + col];
                    float gg = aG[r] + base[(size_t)n * 1872 + 620 + col];
                    float go = aO[r] + base[(size_t)n * 1872 + 1240 + col];
                    float si = 1.f / (1.f + expf(-gi));
                    float so = 1.f / (1.f + expf(-go));
                    float h = so * tanhf(si * tanhf(gg));
                    int pos = (((col >> 5) * 8 + (n >> 4)) * 1024) +
                              (((n & 15) + (((col & 31) >> 3) << 4)) * 8) + (col & 7);
                    unsigned short hi = bf16rne(h);
                    hf[pos] = hi;
                    hf[pos + 512] = bf16rne(h - bf16tof(hi));
                }
            }
            __syncthreads();                // drain hf stores (vmcnt)
            if (tid == 0) {
                __threadfence();            // release hf to IC
                unsigned g = (unsigned)bid >> 3;        // 0..4
                unsigned sz = (g < 4) ? 8u : 7u;
                unsigned a = AADD(&bar[272 + g * 16]);
                if (a == (unsigned)(t + 1) * sz - 1u)
                    AADD(&bar[352]);
            }
        }

        // ---------- all: wait hf(t) ready (flag1 root == 5*(t+1)) ----------
        if (tid < 128) keybuf[tid] = 0ull;
        if (tid == 0)
            while (ALD(&bar[352]) < 5u * (unsigned)(t + 1))
                __builtin_amdgcn_s_sleep(2);
        __syncthreads();

        // ---------- L: B-hi from LDS, B-lo from L2, A depth-4 reg-staged ----------
        f32x4 acc[8];
#pragma unroll
        for (int mt = 0; mt < 8; ++mt) acc[mt] = (f32x4)0.f;

        ISSUE(0);
        ISSUE(1);
        ISSUE(2);
        if (act) { VMW(10); } else { VMW(8); }
        WRA(0);

        LSTEP(0);  LSTEP(1);  LSTEP(2);  LSTEP(3);  LSTEP(4);
        LSTEP(5);  LSTEP(6);  LSTEP(7);  LSTEP(8);  LSTEP(9);
        LSTEP(10); LSTEP(11); LSTEP(12); LSTEP(13); LSTEP(14);
        LSTEP(15); LSTEP(16); LSTEP(17); LSTEP(18); LSTEP(19);

        // ---------- argmax -> slots -> ARRIVE bar2, then out stores ----------
        int q = lane >> 4, cof = lane & 15;
        if (act) {
            int v = myvt * 16 + cof;
            float bwv = bw[v];
#pragma unroll
            for (int mt = 0; mt < 8; ++mt) {
#pragma unroll
                for (int r = 0; r < 4; ++r) {
                    int n = mt * 16 + q * 4 + r;
                    float x = acc[mt][r] + bwv;
                    u64 key = ((u64)ford(x) << 32) | (u64)(0xFFFFFFFFu - (unsigned)v);
#pragma unroll
                    for (int s2 = 1; s2 <= 8; s2 <<= 1) {
                        u64 o = __shfl_xor(key, s2, 64);
                        if (o > key) key = o;
                    }
                    if (cof == 0) atomicMax(&keybuf[n], key);
                }
            }
        }
        __syncthreads();
        if (tid < 128) {
            u64 k = keybuf[tid];
            if (k) atomicMax(&slots[(size_t)t * NSEQ + tid], k);
        }
        __syncthreads();                    // drain slots atomics (vmcnt)
        if (tid == 0) {
            unsigned g = (unsigned)bid >> 4;
            unsigned a = AADD(&bar[g * 16]);
            if (a == (unsigned)(t + 1) * 16u - 1u)
                AADD(&bar[256]);
        }
        // overlapped: out stores for step t (off the critical path)
        if (act) {
            int v = myvt * 16 + cof;
            float bwv = bw[v];
#pragma unroll
            for (int mt = 0; mt < 8; ++mt) {
#pragma unroll
                for (int r = 0; r < 4; ++r) {
                    int n = mt * 16 + q * 4 + r;
                    float x = acc[mt][r] + bwv;
                    __builtin_nontemporal_store(x, &out[((size_t)n * TMAX + t) * VOCAB + v]);
                }
            }
        }
    }
#undef LSTEP
#undef WRA
#undef ISSUE
}

// =====================================================================
// fallback (round-2 proven path) — used only if ws too small for mega
// =====================================================================
__global__ __launch_bounds__(256) void kinit2(unsigned int* lastfrag32,
                                              unsigned int* hfrag32,
                                              unsigned int* slots32,
                                              float* bsum,
                                              const float* __restrict__ b_ih,
                                              const float* __restrict__ b_hh) {
    int i = blockIdx.x * 256 + threadIdx.x;
    if (i < 81920) { lastfrag32[i] = 0u; hfrag32[i] = 0u; }
    if (i < 7680) slots32[i] = 0u;
    if (i < 1872) {
        float v = 0.f;
        if (i < 1860) {
            int row = (i < 620) ? i : i + 620;
            v = b_ih[row] + b_hh[row];
        }
        bsum[i] = v;
    }
}

__global__ __launch_bounds__(256) void klogits2(const unsigned short* __restrict__ Hf,
                                                const unsigned short* __restrict__ Wf,
                                                const float* __restrict__ bw,
                                                float* __restrict__ out,
                                                u64* __restrict__ slots, int t) {
    __shared__ u64 keybuf[128];
    int tid = threadIdx.x;
    if (tid < 128) keybuf[tid] = 0ull;
    __syncthreads();
    int lane = tid & 63, wv = tid >> 6;
    int vtb = blockIdx.x * 8 + wv * 2;
    bool ok0 = vtb < 1250, ok1 = (vtb + 1) < 1250;
    f32x4 acc[8][2];
#pragma unroll
    for (int m = 0; m < 8; ++m) { acc[m][0] = (f32x4)0.f; acc[m][1] = (f32x4)0.f; }
    if (ok0) {
        const unsigned short* ap = Hf + lane * 8;
        const unsigned short* bp0 = Wf + (size_t)vtb * 20 * 1024 + lane * 8;
        const unsigned short* bp1 = bp0 + 20 * 1024;
#pragma unroll 2
        for (int ks = 0; ks < 20; ++ks) {
            short8 b0h = ld8(bp0), b0l = ld8(bp0 + 512);
            short8 ah[8], al[8];
#pragma unroll
            for (int m = 0; m < 8; ++m) {
                ah[m] = ld8(ap + m * 1024);
                al[m] = ld8(ap + m * 1024 + 512);
            }
#pragma unroll
            for (int m = 0; m < 8; ++m) {
                acc[m][0] = MFMA(ah[m], b0h, acc[m][0]);
                acc[m][0] = MFMA(ah[m], b0l, acc[m][0]);
                acc[m][0] = MFMA(al[m], b0h, acc[m][0]);
            }
            if (ok1) {
                short8 b1h = ld8(bp1), b1l = ld8(bp1 + 512);
#pragma unroll
                for (int m = 0; m < 8; ++m) {
                    acc[m][1] = MFMA(ah[m], b1h, acc[m][1]);
                    acc[m][1] = MFMA(ah[m], b1l, acc[m][1]);
                    acc[m][1] = MFMA(al[m], b1h, acc[m][1]);
                }
            }
            ap += 8192; bp0 += 1024; bp1 += 1024;
        }
    }
    int rbase = (lane >> 4) << 2;
    int cof = lane & 15;
    float bw0 = ok0 ? bw[vtb * 16 + cof] : 0.f;
    float bw1 = ok1 ? bw[(vtb + 1) * 16 + cof] : 0.f;
#pragma unroll
    for (int m = 0; m < 8; ++m) {
#pragma unroll
        for (int r = 0; r < 4; ++r) {
            int row = m * 16 + rbase + r;
            u64 km = 0ull;
            if (ok0) {
                int v = vtb * 16 + cof;
                float x = acc[m][0][r] + bw0;
                out[((size_t)row * TMAX + t) * VOCAB + v] = x;
                km = ((u64)ford(x) << 32) | (u64)(0xFFFFFFFFu - (unsigned)v);
            }
            if (ok1) {
                int v = (vtb + 1) * 16 + cof;
                float x = acc[m][1][r] + bw1;
                out[((size_t)row * TMAX + t) * VOCAB + v] = x;
                u64 k2 = ((u64)ford(x) << 32) | (u64)(0xFFFFFFFFu - (unsigned)v);
                if (k2 > km) km = k2;
            }
#pragma unroll
            for (int s2 = 1; s2 <= 8; s2 <<= 1) {
                u64 o = __shfl_xor(km, s2, 64);
                if (o > km) km = o;
            }
            if ((lane & 15) == 0 && km) atomicMax(&keybuf[row], km);
        }
    }
    __syncthreads();
    if (tid < 128) atomicMax(&slots[(size_t)t * NSEQ + tid], keybuf[tid]);
}

__global__ void kact(const float* __restrict__ gates,
                     unsigned short* __restrict__ hfrag) {
    int n = blockIdx.x;
    int k = threadIdx.x;
    if (k >= WORD) return;
    const float* g = gates + (size_t)n * 1872;
    float gi = g[k], gg = g[620 + k], go = g[1240 + k];
    float si = 1.f / (1.f + expf(-gi));
    float so = 1.f / (1.f + expf(-go));
    float h = so * tanhf(si * tanhf(gg));
    int ks = k >> 5, mt = n >> 4;
    int lane = (n & 15) + (((k & 31) >> 3) << 4);
    int j = k & 7;
    size_t ob = (size_t)(ks * 8 + mt) * 1024 + lane * 8 + j;
    unsigned short hi = bf16rne(h);
    hfrag[ob] = hi;
    hfrag[ob + 512] = bf16rne(h - bf16tof(hi));
}

__global__ void kgather2(const float* __restrict__ embed,
                         const u64* __restrict__ slots,
                         unsigned short* __restrict__ lastfrag, int t) {
    int n = blockIdx.x;
    int k = threadIdx.x;
    if (k >= WORD) return;
    u64 s = slots[(size_t)t * NSEQ + n];
    unsigned idx = 0xFFFFFFFFu - (unsigned)(s & 0xFFFFFFFFull);
    float x = embed[(size_t)idx * WORD + k];
    int ks = k >> 5, mt = n >> 4;
    int lane = (n & 15) + (((k & 31) >> 3) << 4);
    int j = k & 7;
    size_t ob = (size_t)(ks * 8 + mt) * 1024 + lane * 8 + j;
    unsigned short hi = bf16rne(x);
    lastfrag[ob] = hi;
    lastfrag[ob + 512] = bf16rne(x - bf16tof(hi));
}

// =====================================================================
extern "C" void kernel_launch(void* const* d_in, const int* in_sizes, int n_in,
                              void* d_out, int out_size, void* d_ws, size_t ws_size,
                              hipStream_t stream) {
    const float* thoughts = (const float*)d_in[0];
    const float* embed    = (const float*)d_in[1];
    const float* W_ih     = (const float*)d_in[2];
    // d_in[3] = W_hh: dead (h0 == 0 always)
    const float* b_ih     = (const float*)d_in[4];
    const float* b_hh     = (const float*)d_in[5];
    const float* Ww       = (const float*)d_in[6];
    const float* bw       = (const float*)d_in[7];
    float* out = (float*)d_out;
    char* ws = (char*)d_ws;

    // mega layout
    const size_t OFF_WWF  = 0;              // 51,200,000
    const size_t OFF_WBF  = 51200000;       // 17,971,200
    const size_t OFF_WGF3 = 69171200;       //  4,792,320
    const size_t OFF_CTXF = 73963520;       //  1,228,800
    const size_t OFF_EHI  = 75192320;       // 25,600,000
    const size_t OFF_ELO  = 100792320;      // 25,600,000
    const size_t OFF_HF   = 126392320;      //    327,680
    const size_t OFF_BASE = 126720000;      //    958,464
    const size_t OFF_BSUM = 127678464;      //      7,488
    const size_t OFF_SLOT = 127685952;      //     30,720
    const size_t OFF_BAR  = 127716672;      //      2,048
    const size_t NEED_MEGA = 127718720;

    if (ws_size >= NEED_MEGA) {
        unsigned short* Wwf  = (unsigned short*)(ws + OFF_WWF);
        unsigned short* Wbf  = (unsigned short*)(ws + OFF_WBF);
        unsigned short* Wgf3 = (unsigned short*)(ws + OFF_WGF3);
        unsigned short* ctxf = (unsigned short*)(ws + OFF_CTXF);
        unsigned short* ehi  = (unsigned short*)(ws + OFF_EHI);
        unsigned short* elo  = (unsigned short*)(ws + OFF_ELO);
        unsigned short* hf   = (unsigned short*)(ws + OFF_HF);
        float* base = (float*)(ws + OFF_BASE);
        float* bsum = (float*)(ws + OFF_BSUM);
        u64*   slots = (u64*)(ws + OFF_SLOT);
        unsigned* bar = (unsigned*)(ws + OFF_BAR);

        kinit3<<<320, 256, 0, stream>>>((unsigned*)hf, (unsigned*)slots, bsum, bar, b_ih, b_hh);
        kpack_w<<<50000, 256, 0, stream>>>(Ww, Wwf, 1250, 20, 0, 620, WORD, VOCAB, 0);
        kpack_w<<<17550, 256, 0, stream>>>(W_ih, Wbf, 117, 75, 0, 2400, XK, 1860, 1);
        kpack_w<<<1560, 256, 0, stream>>>(W_ih + (size_t)0 * XK,    Wgf3 + 0 * 798720, 39, 20, 2400, 620, XK, 620, 0);
        kpack_w<<<1560, 256, 0, stream>>>(W_ih + (size_t)1240 * XK, Wgf3 + 1 * 798720, 39, 20, 2400, 620, XK, 620, 0);
        kpack_w<<<1560, 256, 0, stream>>>(W_ih + (size_t)1860 * XK, Wgf3 + 2 * 798720, 39, 20, 2400, 620, XK, 620, 0);
        kpack_ctx<<<1200, 256, 0, stream>>>(thoughts, ctxf);
        kpack_embed<<<50000, 256, 0, stream>>>(embed, ehi, elo);
        ggemm<<<15, 256, 0, stream>>>(ctxf, Wbf, bsum, nullptr, base, 75, 117, 1872);

        kmega<<<NBLK, 512, 0, stream>>>(ehi, elo, Wgf3, Wwf, base, bw, hf, slots, out, bar);
    } else {
        // round-2 fallback layout
        const size_t F_WWF  = 0;
        const size_t F_WBF  = 51200000;
        const size_t F_WGF  = 69171200;
        const size_t F_CTXF = 73963520;
        const size_t F_HF   = 75192320;
        const size_t F_LF   = 75520000;
        const size_t F_BASE = 75847680;
        const size_t F_GATE = 76806144;
        const size_t F_BSUM = 77764608;
        const size_t F_SLOT = 77772096;

        unsigned short* Wwf  = (unsigned short*)(ws + F_WWF);
        unsigned short* Wbf  = (unsigned short*)(ws + F_WBF);
        unsigned short* Wgf  = (unsigned short*)(ws + F_WGF);
        unsigned short* ctxf = (unsigned short*)(ws + F_CTXF);
        unsigned short* hf   = (unsigned short*)(ws + F_HF);
        unsigned short* lf   = (unsigned short*)(ws + F_LF);
        float* base = (float*)(ws + F_BASE);
        float* gate = (float*)(ws + F_GATE);
        float* bsum = (float*)(ws + F_BSUM);
        u64*   slots = (u64*)(ws + F_SLOT);

        kinit2<<<320, 256, 0, stream>>>((unsigned int*)lf, (unsigned int*)hf,
                                        (unsigned int*)slots, bsum, b_ih, b_hh);
        kpack_w<<<50000, 256, 0, stream>>>(Ww, Wwf, 1250, 20, 0, 620, WORD, VOCAB, 0);
        kpack_w<<<17550, 256, 0, stream>>>(W_ih, Wbf, 117, 75, 0, 2400, XK, 1860, 1);
        kpack_w<<<4680, 256, 0, stream>>>(W_ih, Wgf, 117, 20, 2400, 620, XK, 1860, 1);
        kpack_ctx<<<1200, 256, 0, stream>>>(thoughts, ctxf);
        ggemm<<<15, 256, 0, stream>>>(ctxf, Wbf, bsum, nullptr, base, 75, 117, 1872);
        for (int t = 0; t < TMAX; ++t) {
            ggemm<<<15, 256, 0, stream>>>(lf, Wgf, nullptr, base, gate, 20, 117, 1872);
            kact<<<NSEQ, 640, 0, stream>>>(gate, hf);
            klogits2<<<157, 256, 0, stream>>>(hf, Wwf, bw, out, slots, t);
            if (t + 1 < TMAX)
                kgather2<<<NSEQ, 640, 0, stream>>>(embed, slots, lf, t);
        }
    }
}

// Round 16
// 1545.766 us; speedup vs baseline: 1.0169x; 1.0169x over previous
//
#include <hip/hip_runtime.h>
#include <math.h>

#define VOCAB 20000
#define WORD 620
#define NSEQ 128
#define TMAX 30
#define CTXK 2400
#define XK 3020
#define NBLK 256

typedef unsigned long long u64;
typedef __attribute__((ext_vector_type(8))) short short8;
typedef __attribute__((ext_vector_type(4))) float f32x4;

// ---------- helpers ----------
__device__ __forceinline__ unsigned ford(float f) {
    unsigned b = __float_as_uint(f);
    return (b & 0x80000000u) ? ~b : (b | 0x80000000u);
}
__device__ __forceinline__ unsigned short bf16rne(float x) {
    unsigned u = __float_as_uint(x);
    return (unsigned short)((u + 0x7fffu + ((u >> 16) & 1u)) >> 16);
}
__device__ __forceinline__ float bf16tof(unsigned short h) {
    return __uint_as_float(((unsigned)h) << 16);
}
__device__ __forceinline__ short8 ld8(const unsigned short* p) {
    return *(const short8*)p;
}
#define MFMA(a, b, c) __builtin_amdgcn_mfma_f32_16x16x32_bf16((a), (b), (c), 0, 0, 0)
#define VMW(N) asm volatile("s_waitcnt vmcnt(" #N ")" ::: "memory")
#define AL64(p) __hip_atomic_load((p), __ATOMIC_RELAXED, __HIP_MEMORY_SCOPE_AGENT)
#define AADD(p) __hip_atomic_fetch_add((p), 1u, __ATOMIC_RELAXED, __HIP_MEMORY_SCOPE_AGENT)
#define ALD(p) __hip_atomic_load((p), __ATOMIC_RELAXED, __HIP_MEMORY_SCOPE_AGENT)

// async 16B/lane global->LDS copy; LDS dest = uniform base + lane*16
__device__ __forceinline__ void gload_lds16(const void* g, void* l) {
    __builtin_amdgcn_global_load_lds((const __attribute__((address_space(1))) void*)g,
                                     (__attribute__((address_space(3))) void*)l,
                                     16, 0, 0);
}

// =====================================================================
// Shared fragment layout (m91-verified trio), all buffers [tile][ks][2][64][8]:
//   A frag: lane holds A[row = mt*16 + lane%16][k = ks*32 + (lane/16)*8 + j]
//   B frag: lane holds B[col = vt*16 + lane%16][k = ...same...]
//   C/D:    row = (lane>>4)*4 + r, col = lane&15
// =====================================================================

__global__ __launch_bounds__(256) void kpack_w(const float* __restrict__ src,
                                               unsigned short* __restrict__ dst,
                                               int nvt, int nks, int col0,
                                               int ncols_valid, int src_ld,
                                               int nrows_valid, int rowmap) {
    int i = blockIdx.x * 256 + threadIdx.x;
    if (i >= nvt * nks * 512) return;
    int j = i & 7;
    int lane = (i >> 3) & 63;
    int t2 = i >> 9;
    int ks = t2 % nks;
    int vt = t2 / nks;
    int r = vt * 16 + (lane & 15);
    int k = ks * 32 + ((lane >> 4) << 3) + j;
    float x = 0.f;
    if (r < nrows_valid && k < ncols_valid) {
        int row = (rowmap == 1) ? ((r < 620) ? r : r + 620) : r;
        x = src[(size_t)row * src_ld + col0 + k];
    }
    unsigned short hi = bf16rne(x);
    unsigned short lo = bf16rne(x - bf16tof(hi));
    size_t ob = (size_t)t2 * 1024 + lane * 8 + j;
    dst[ob] = hi;
    dst[ob + 512] = lo;
}

__global__ __launch_bounds__(256) void kpack_ctx(const float* __restrict__ th,
                                                 unsigned short* __restrict__ dst) {
    int i = blockIdx.x * 256 + threadIdx.x;
    if (i >= 75 * 8 * 512) return;
    int j = i & 7;
    int lane = (i >> 3) & 63;
    int t2 = i >> 9;
    int mt = t2 & 7;
    int ks = t2 >> 3;
    int n = mt * 16 + (lane & 15);
    int k = ks * 32 + ((lane >> 4) << 3) + j;
    float x = (k < 1200) ? th[(size_t)n * 1200 + k]
                         : th[(size_t)(n + 2) * 1200 + (k - 1200)];
    unsigned short hi = bf16rne(x);
    unsigned short lo = bf16rne(x - bf16tof(hi));
    size_t ob = (size_t)t2 * 1024 + lane * 8 + j;
    dst[ob] = hi;
    dst[ob + 512] = lo;
}

__global__ __launch_bounds__(256) void kpack_embed(const float* __restrict__ embed,
                                                   unsigned short* __restrict__ ehi,
                                                   unsigned short* __restrict__ elo) {
    size_t i = (size_t)blockIdx.x * 256 + threadIdx.x;
    if (i >= (size_t)VOCAB * 640) return;
    int v = (int)(i / 640);
    int k = (int)(i % 640);
    float x = (k < WORD) ? embed[(size_t)v * WORD + k] : 0.f;
    unsigned short hi = bf16rne(x);
    ehi[i] = hi;
    elo[i] = bf16rne(x - bf16tof(hi));
}

// generic frag GEMM (setup only): outT[row][col] = A@B^T (+addRow)
__global__ __launch_bounds__(256) void ggemm(const unsigned short* __restrict__ Af,
                                             const unsigned short* __restrict__ Bf,
                                             const float* __restrict__ addRow,
                                             const float* __restrict__ addFull,
                                             float* __restrict__ outT,
                                             int nks, int nvt, int ldout) {
    int lane = threadIdx.x & 63, wv = threadIdx.x >> 6;
    int vtb = blockIdx.x * 8 + wv * 2;
    bool ok0 = vtb < nvt, ok1 = (vtb + 1) < nvt;
    f32x4 acc[8][2];
#pragma unroll
    for (int m = 0; m < 8; ++m) { acc[m][0] = (f32x4)0.f; acc[m][1] = (f32x4)0.f; }
    if (ok0) {
        const unsigned short* ap = Af + lane * 8;
        const unsigned short* bp0 = Bf + (size_t)vtb * nks * 1024 + lane * 8;
        const unsigned short* bp1 = bp0 + (size_t)nks * 1024;
        for (int ks = 0; ks < nks; ++ks) {
            short8 b0h = ld8(bp0), b0l = ld8(bp0 + 512);
            short8 ah[8], al[8];
#pragma unroll
            for (int m = 0; m < 8; ++m) {
                ah[m] = ld8(ap + m * 1024);
                al[m] = ld8(ap + m * 1024 + 512);
            }
#pragma unroll
            for (int m = 0; m < 8; ++m) {
                acc[m][0] = MFMA(ah[m], b0h, acc[m][0]);
                acc[m][0] = MFMA(ah[m], b0l, acc[m][0]);
                acc[m][0] = MFMA(al[m], b0h, acc[m][0]);
            }
            if (ok1) {
                short8 b1h = ld8(bp1), b1l = ld8(bp1 + 512);
#pragma unroll
                for (int m = 0; m < 8; ++m) {
                    acc[m][1] = MFMA(ah[m], b1h, acc[m][1]);
                    acc[m][1] = MFMA(ah[m], b1l, acc[m][1]);
                    acc[m][1] = MFMA(al[m], b1h, acc[m][1]);
                }
            }
            ap += 8192; bp0 += 1024; bp1 += 1024;
        }
    }
    int rbase = (lane >> 4) << 2;
    int cof = lane & 15;
#pragma unroll
    for (int v = 0; v < 2; ++v) {
        bool ok = v ? ok1 : ok0;
        if (!ok) continue;
        int col = (vtb + v) * 16 + cof;
        float ar = addRow ? addRow[col] : 0.f;
#pragma unroll
        for (int m = 0; m < 8; ++m) {
#pragma unroll
            for (int r = 0; r < 4; ++r) {
                int row = m * 16 + rbase + r;
                float x = acc[m][v][r] + ar;
                if (addFull) x += addFull[(size_t)row * ldout + col];
                outT[(size_t)row * ldout + col] = x;
            }
        }
    }
}

// init for mega path (hf rotation needs NO zeroing: fully written each step)
__global__ __launch_bounds__(256) void kinit3(unsigned* slots32,
                                              float* bsum, unsigned* bar,
                                              const float* __restrict__ b_ih,
                                              const float* __restrict__ b_hh) {
    int i = blockIdx.x * 256 + threadIdx.x;
    if (i < 7680) slots32[i] = 0u;
    if (i < 512) bar[i] = 0u;
    if (i < 1872) {
        float v = 0.f;
        if (i < 1860) {
            int row = (i < 620) ? i : i + 620;   // [i, g, o] -> W_ih rows
            v = b_ih[row] + b_hh[row];
        }
        bsum[i] = v;
    }
}

// =====================================================================
// Persistent decode kernel v13 = round-14/15 math (bit-identical) +
// PER-STEP hf ROTATION: hf_t = hfrot + t*163840 occupies fresh addresses
// every step -> readers use PLAIN CACHED loads (L2 can't hold stale
// copies of never-seen lines; it fetches from IC where G's release fence
// put the data). IC traffic for A drops 256x -> 8 XCD fetches/step.
// G extended to 40 blocks so cols 620-639 are zero-written each step
// (no pre-zeroing of the rotation buffers needed).
// =====================================================================
__global__ __launch_bounds__(512, 2) void kmega(
    const unsigned short* __restrict__ embhi,
    const unsigned short* __restrict__ emblo,
    const unsigned short* __restrict__ Wgf3,
    const unsigned short* __restrict__ Wwf,
    const float* __restrict__ base,
    const float* __restrict__ bw,
    unsigned short* __restrict__ hfrot,
    u64* __restrict__ slots,
    float* __restrict__ out,
    unsigned* bar) {
    __shared__ char sBhi[102400];              // [vt_local][ks][1024B]
    __shared__ char sA[3][16384];
    __shared__ u64 keybuf[128];
    const int tid = threadIdx.x;
    const int lane = tid & 63;
    const int wv = tid >> 6;                   // 0..7
    const int bid = blockIdx.x;

    const int vt_lo = (int)(((long long)bid * 1250) / NBLK);
    const int vt_hi = (int)(((long long)(bid + 1) * 1250) / NBLK);
    const int nvt = vt_hi - vt_lo;             // 4 or 5
    const bool act = (wv < nvt);               // wave owns one vt
    const int myvt = vt_lo + (act ? wv : 0);
    const bool gact = (bid < 40);              // 40 G-blocks cover cols 0..639

    const char* wwb = (const char*)Wwf;
    const unsigned short* BbaseLo = Wwf + (size_t)myvt * 20480 + 512 + lane * 8;

    // ---- one-time: stage B-hi (nvt*20 lines of 1 KB) into LDS ----
    for (int i = wv; i < nvt * 20; i += 8) {
        const char* g = wwb + (size_t)(vt_lo + i / 20) * 40960 + (size_t)(i % 20) * 2048 + lane * 16;
        gload_lds16(g, sBhi + (size_t)i * 1024);
    }
    VMW(0);
    __syncthreads();

    short8 RA[3][2];
    short8 Bl[4];

#define ISSUE(M, HFT)                                                          \
    do {                                                                       \
        const unsigned short* ga_ = (HFT) + (size_t)(M) * 8192 +               \
                                    wv * 1024 + lane * 8;                      \
        RA[(M) % 3][0] = ld8(ga_);                                             \
        RA[(M) % 3][1] = ld8(ga_ + 512);                                       \
        if (act) Bl[(M) % 4] = ld8(BbaseLo + (size_t)(M) * 1024);              \
    } while (0)

#define WRA(M)                                                                 \
    do {                                                                       \
        char* da_ = sA[(M) % 3] + wv * 2048 + lane * 16;                       \
        *(short8*)da_ = RA[(M) % 3][0];                                        \
        *(short8*)(da_ + 1024) = RA[(M) % 3][1];                               \
    } while (0)

// per-chunk per-wave vmem ops: act ? 3 : 2 (2 A loads + 1 B-lo load)
#define LSTEP(K, HFT)                                                          \
    do {                                                                       \
        if ((K) + 3 < 20) ISSUE((K) + 3, HFT);                                 \
        if ((K) <= 16) { if (act) { VMW(6); } else { VMW(4); } }               \
        else if ((K) == 17) { if (act) { VMW(3); } else { VMW(2); } }          \
        else { VMW(0); }                                                       \
        if ((K) + 1 < 20) WRA((K) + 1);                                        \
        asm volatile("s_waitcnt lgkmcnt(0)" ::: "memory");                     \
        __builtin_amdgcn_s_barrier();                                          \
        __builtin_amdgcn_sched_barrier(0);                                     \
        if (act) {                                                             \
            const unsigned short* ab_ = (const unsigned short*)sA[(K) % 3];    \
            short8 bh_ = ld8((const unsigned short*)(sBhi +                    \
                             (size_t)(wv * 20 + (K)) * 1024) + lane * 8);      \
            _Pragma("unroll")                                                  \
            for (int mt = 0; mt < 8; ++mt) {                                   \
                short8 ah_ = ld8(ab_ + mt * 1024 + lane * 8);                  \
                short8 al_ = ld8(ab_ + mt * 1024 + 512 + lane * 8);            \
                acc[mt] = MFMA(ah_, bh_, acc[mt]);                             \
                acc[mt] = MFMA(ah_, Bl[(K) % 4], acc[mt]);                     \
                acc[mt] = MFMA(al_, bh_, acc[mt]);                             \
            }                                                                  \
        }                                                                      \
    } while (0)

    for (int t = 0; t < TMAX; ++t) {
        unsigned short* hft = hfrot + (size_t)t * 163840;
        // ---------- G: gates + activation -> hft (G-blocks only) ----------
        if (gact) {
            if (t > 0) {
                if (tid == 0)
                    while (ALD(&bar[256]) < 16u * (unsigned)t)
                        __builtin_amdgcn_s_sleep(2);
                __syncthreads();
            }
            const int g_vt = bid;              // 0..39
            const int g_mt = wv;               // 0..7
            f32x4 aI = (f32x4)0.f, aG = (f32x4)0.f, aO = (f32x4)0.f;
            if (t > 0 && g_vt < 39) {
                int n = g_mt * 16 + (lane & 15);
                u64 s = AL64(&slots[(size_t)(t - 1) * NSEQ + n]);
                unsigned idx = 0xFFFFFFFFu - (unsigned)(s & 0xFFFFFFFFull);
                const unsigned short* eh = embhi + (size_t)idx * 640 + ((lane >> 4) << 3);
                const unsigned short* el = emblo + (size_t)idx * 640 + ((lane >> 4) << 3);
                const unsigned short* bI = Wgf3 + (size_t)(0 * 39 + g_vt) * 20480 + lane * 8;
                const unsigned short* bG = Wgf3 + (size_t)(1 * 39 + g_vt) * 20480 + lane * 8;
                const unsigned short* bO = Wgf3 + (size_t)(2 * 39 + g_vt) * 20480 + lane * 8;
#pragma unroll 2
                for (int ks = 0; ks < 20; ++ks) {
                    short8 ah = ld8(eh + ks * 32);
                    short8 al = ld8(el + ks * 32);
                    short8 bIh = ld8(bI), bIl = ld8(bI + 512);
                    short8 bGh = ld8(bG), bGl = ld8(bG + 512);
                    short8 bOh = ld8(bO), bOl = ld8(bO + 512);
                    aI = MFMA(ah, bIh, aI); aI = MFMA(ah, bIl, aI); aI = MFMA(al, bIh, aI);
                    aG = MFMA(ah, bGh, aG); aG = MFMA(ah, bGl, aG); aG = MFMA(al, bGh, aG);
                    aO = MFMA(ah, bOh, aO); aO = MFMA(ah, bOl, aO); aO = MFMA(al, bOh, aO);
                    bI += 1024; bG += 1024; bO += 1024;
                }
            }
            int col = g_vt * 16 + (lane & 15);
            int rbase = g_mt * 16 + ((lane >> 4) << 2);
#pragma unroll
            for (int r = 0; r < 4; ++r) {
                int n = rbase + r;
                float h = 0.f;
                if (col < WORD) {
                    float gi = aI[r] + base[(size_t)n * 1872 + col];
                    float gg = aG[r] + base[(size_t)n * 1872 + 620 + col];
                    float go = aO[r] + base[(size_t)n * 1872 + 1240 + col];
                    float si = 1.f / (1.f + expf(-gi));
                    float so = 1.f / (1.f + expf(-go));
                    h = so * tanhf(si * tanhf(gg));
                }
                int pos = (((col >> 5) * 8 + (n >> 4)) * 1024) +
                          (((n & 15) + (((col & 31) >> 3) << 4)) * 8) + (col & 7);
                unsigned short hi = bf16rne(h);
                hft[pos] = hi;
                hft[pos + 512] = bf16rne(h - bf16tof(hi));
            }
            __syncthreads();                // drain hft stores (vmcnt)
            if (tid == 0) {
                __threadfence();            // release hft to IC
                unsigned g = (unsigned)bid >> 3;        // 0..4, 8 blocks each
                unsigned a = AADD(&bar[272 + g * 16]);
                if (a == (unsigned)(t + 1) * 8u - 1u)
                    AADD(&bar[352]);
            }
        }

        // ---------- all: wait hf(t) ready (flag1 root == 5*(t+1)) ----------
        if (tid < 128) keybuf[tid] = 0ull;
        if (tid == 0)
            while (ALD(&bar[352]) < 5u * (unsigned)(t + 1))
                __builtin_amdgcn_s_sleep(2);
        __syncthreads();

        // ---------- L: B-hi LDS, B-lo L2, A cached-load depth-3 ----------
        f32x4 acc[8];
#pragma unroll
        for (int mt = 0; mt < 8; ++mt) acc[mt] = (f32x4)0.f;

        ISSUE(0, hft);
        ISSUE(1, hft);
        ISSUE(2, hft);
        if (act) { VMW(6); } else { VMW(4); }
        WRA(0);

        LSTEP(0, hft);  LSTEP(1, hft);  LSTEP(2, hft);  LSTEP(3, hft);  LSTEP(4, hft);
        LSTEP(5, hft);  LSTEP(6, hft);  LSTEP(7, hft);  LSTEP(8, hft);  LSTEP(9, hft);
        LSTEP(10, hft); LSTEP(11, hft); LSTEP(12, hft); LSTEP(13, hft); LSTEP(14, hft);
        LSTEP(15, hft); LSTEP(16, hft); LSTEP(17, hft); LSTEP(18, hft); LSTEP(19, hft);

        // ---------- argmax -> slots -> ARRIVE bar2, then out stores ----------
        int q = lane >> 4, cof = lane & 15;
        if (act) {
            int v = myvt * 16 + cof;
            float bwv = bw[v];
#pragma unroll
            for (int mt = 0; mt < 8; ++mt) {
#pragma unroll
                for (int r = 0; r < 4; ++r) {
                    int n = mt * 16 + q * 4 + r;
                    float x = acc[mt][r] + bwv;
                    u64 key = ((u64)ford(x) << 32) | (u64)(0xFFFFFFFFu - (unsigned)v);
#pragma unroll
                    for (int s2 = 1; s2 <= 8; s2 <<= 1) {
                        u64 o = __shfl_xor(key, s2, 64);
                        if (o > key) key = o;
                    }
                    if (cof == 0) atomicMax(&keybuf[n], key);
                }
            }
        }
        __syncthreads();
        if (tid < 128) {
            u64 k = keybuf[tid];
            if (k) atomicMax(&slots[(size_t)t * NSEQ + tid], k);
        }
        __syncthreads();                    // drain slots atomics (vmcnt)
        if (tid == 0) {
            unsigned g = (unsigned)bid >> 4;
            unsigned a = AADD(&bar[g * 16]);
            if (a == (unsigned)(t + 1) * 16u - 1u)
                AADD(&bar[256]);
        }
        // overlapped: out stores for step t (off the critical path)
        if (act) {
            int v = myvt * 16 + cof;
            float bwv = bw[v];
#pragma unroll
            for (int mt = 0; mt < 8; ++mt) {
#pragma unroll
                for (int r = 0; r < 4; ++r) {
                    int n = mt * 16 + q * 4 + r;
                    float x = acc[mt][r] + bwv;
                    __builtin_nontemporal_store(x, &out[((size_t)n * TMAX + t) * VOCAB + v]);
                }
            }
        }
    }
#undef LSTEP
#undef WRA
#undef ISSUE
}

// =====================================================================
// fallback (round-2 proven path) — used only if ws too small for mega
// =====================================================================
__global__ __launch_bounds__(256) void kinit2(unsigned int* lastfrag32,
                                              unsigned int* hfrag32,
                                              unsigned int* slots32,
                                              float* bsum,
                                              const float* __restrict__ b_ih,
                                              const float* __restrict__ b_hh) {
    int i = blockIdx.x * 256 + threadIdx.x;
    if (i < 81920) { lastfrag32[i] = 0u; hfrag32[i] = 0u; }
    if (i < 7680) slots32[i] = 0u;
    if (i < 1872) {
        float v = 0.f;
        if (i < 1860) {
            int row = (i < 620) ? i : i + 620;
            v = b_ih[row] + b_hh[row];
        }
        bsum[i] = v;
    }
}

__global__ __launch_bounds__(256) void klogits2(const unsigned short* __restrict__ Hf,
                                                const unsigned short* __restrict__ Wf,
                                                const float* __restrict__ bw,
                                                float* __restrict__ out,
                                                u64* __restrict__ slots, int t) {
    __shared__ u64 keybuf[128];
    int tid = threadIdx.x;
    if (tid < 128) keybuf[tid] = 0ull;
    __syncthreads();
    int lane = tid & 63, wv = tid >> 6;
    int vtb = blockIdx.x * 8 + wv * 2;
    bool ok0 = vtb < 1250, ok1 = (vtb + 1) < 1250;
    f32x4 acc[8][2];
#pragma unroll
    for (int m = 0; m < 8; ++m) { acc[m][0] = (f32x4)0.f; acc[m][1] = (f32x4)0.f; }
    if (ok0) {
        const unsigned short* ap = Hf + lane * 8;
        const unsigned short* bp0 = Wf + (size_t)vtb * 20 * 1024 + lane * 8;
        const unsigned short* bp1 = bp0 + 20 * 1024;
#pragma unroll 2
        for (int ks = 0; ks < 20; ++ks) {
            short8 b0h = ld8(bp0), b0l = ld8(bp0 + 512);
            short8 ah[8], al[8];
#pragma unroll
            for (int m = 0; m < 8; ++m) {
                ah[m] = ld8(ap + m * 1024);
                al[m] = ld8(ap + m * 1024 + 512);
            }
#pragma unroll
            for (int m = 0; m < 8; ++m) {
                acc[m][0] = MFMA(ah[m], b0h, acc[m][0]);
                acc[m][0] = MFMA(ah[m], b0l, acc[m][0]);
                acc[m][0] = MFMA(al[m], b0h, acc[m][0]);
            }
            if (ok1) {
                short8 b1h = ld8(bp1), b1l = ld8(bp1 + 512);
#pragma unroll
                for (int m = 0; m < 8; ++m) {
                    acc[m][1] = MFMA(ah[m], b1h, acc[m][1]);
                    acc[m][1] = MFMA(ah[m], b1l, acc[m][1]);
                    acc[m][1] = MFMA(al[m], b1h, acc[m][1]);
                }
            }
            ap += 8192; bp0 += 1024; bp1 += 1024;
        }
    }
    int rbase = (lane >> 4) << 2;
    int cof = lane & 15;
    float bw0 = ok0 ? bw[vtb * 16 + cof] : 0.f;
    float bw1 = ok1 ? bw[(vtb + 1) * 16 + cof] : 0.f;
#pragma unroll
    for (int m = 0; m < 8; ++m) {
#pragma unroll
        for (int r = 0; r < 4; ++r) {
            int row = m * 16 + rbase + r;
            u64 km = 0ull;
            if (ok0) {
                int v = vtb * 16 + cof;
                float x = acc[m][0][r] + bw0;
                out[((size_t)row * TMAX + t) * VOCAB + v] = x;
                km = ((u64)ford(x) << 32) | (u64)(0xFFFFFFFFu - (unsigned)v);
            }
            if (ok1) {
                int v = (vtb + 1) * 16 + cof;
                float x = acc[m][1][r] + bw1;
                out[((size_t)row * TMAX + t) * VOCAB + v] = x;
                u64 k2 = ((u64)ford(x) << 32) | (u64)(0xFFFFFFFFu - (unsigned)v);
                if (k2 > km) km = k2;
            }
#pragma unroll
            for (int s2 = 1; s2 <= 8; s2 <<= 1) {
                u64 o = __shfl_xor(km, s2, 64);
                if (o > km) km = o;
            }
            if ((lane & 15) == 0 && km) atomicMax(&keybuf[row], km);
        }
    }
    __syncthreads();
    if (tid < 128) atomicMax(&slots[(size_t)t * NSEQ + tid], keybuf[tid]);
}

__global__ void kact(const float* __restrict__ gates,
                     unsigned short* __restrict__ hfrag) {
    int n = blockIdx.x;
    int k = threadIdx.x;
    if (k >= WORD) return;
    const float* g = gates + (size_t)n * 1872;
    float gi = g[k], gg = g[620 + k], go = g[1240 + k];
    float si = 1.f / (1.f + expf(-gi));
    float so = 1.f / (1.f + expf(-go));
    float h = so * tanhf(si * tanhf(gg));
    int ks = k >> 5, mt = n >> 4;
    int lane = (n & 15) + (((k & 31) >> 3) << 4);
    int j = k & 7;
    size_t ob = (size_t)(ks * 8 + mt) * 1024 + lane * 8 + j;
    unsigned short hi = bf16rne(h);
    hfrag[ob] = hi;
    hfrag[ob + 512] = bf16rne(h - bf16tof(hi));
}

__global__ void kgather2(const float* __restrict__ embed,
                         const u64* __restrict__ slots,
                         unsigned short* __restrict__ lastfrag, int t) {
    int n = blockIdx.x;
    int k = threadIdx.x;
    if (k >= WORD) return;
    u64 s = slots[(size_t)t * NSEQ + n];
    unsigned idx = 0xFFFFFFFFu - (unsigned)(s & 0xFFFFFFFFull);
    float x = embed[(size_t)idx * WORD + k];
    int ks = k >> 5, mt = n >> 4;
    int lane = (n & 15) + (((k & 31) >> 3) << 4);
    int j = k & 7;
    size_t ob = (size_t)(ks * 8 + mt) * 1024 + lane * 8 + j;
    unsigned short hi = bf16rne(x);
    lastfrag[ob] = hi;
    lastfrag[ob + 512] = bf16rne(x - bf16tof(hi));
}

// =====================================================================
extern "C" void kernel_launch(void* const* d_in, const int* in_sizes, int n_in,
                              void* d_out, int out_size, void* d_ws, size_t ws_size,
                              hipStream_t stream) {
    const float* thoughts = (const float*)d_in[0];
    const float* embed    = (const float*)d_in[1];
    const float* W_ih     = (const float*)d_in[2];
    // d_in[3] = W_hh: dead (h0 == 0 always)
    const float* b_ih     = (const float*)d_in[4];
    const float* b_hh     = (const float*)d_in[5];
    const float* Ww       = (const float*)d_in[6];
    const float* bw       = (const float*)d_in[7];
    float* out = (float*)d_out;
    char* ws = (char*)d_ws;

    // mega layout (hf rotation ALIASES the setup-only Wbf region: ggemm
    // finishes before kmega starts, and every hf_t is fully written by G
    // before any read, so no zeroing needed)
    const size_t OFF_WWF  = 0;              // 51,200,000
    const size_t OFF_WBF  = 51200000;       // 17,971,200 (-> hf rotation, 9,830,400)
    const size_t OFF_WGF3 = 69171200;       //  4,792,320
    const size_t OFF_CTXF = 73963520;       //  1,228,800
    const size_t OFF_EHI  = 75192320;       // 25,600,000
    const size_t OFF_ELO  = 100792320;      // 25,600,000
    const size_t OFF_BASE = 126392320;      //    958,464
    const size_t OFF_BSUM = 127350784;      //      7,488
    const size_t OFF_SLOT = 127358272;      //     30,720
    const size_t OFF_BAR  = 127388992;      //      2,048
    const size_t NEED_MEGA = 127391040;

    if (ws_size >= NEED_MEGA) {
        unsigned short* Wwf  = (unsigned short*)(ws + OFF_WWF);
        unsigned short* Wbf  = (unsigned short*)(ws + OFF_WBF);
        unsigned short* hfrot = (unsigned short*)(ws + OFF_WBF);   // alias (post-setup)
        unsigned short* Wgf3 = (unsigned short*)(ws + OFF_WGF3);
        unsigned short* ctxf = (unsigned short*)(ws + OFF_CTXF);
        unsigned short* ehi  = (unsigned short*)(ws + OFF_EHI);
        unsigned short* elo  = (unsigned short*)(ws + OFF_ELO);
        float* base = (float*)(ws + OFF_BASE);
        float* bsum = (float*)(ws + OFF_BSUM);
        u64*   slots = (u64*)(ws + OFF_SLOT);
        unsigned* bar = (unsigned*)(ws + OFF_BAR);

        kinit3<<<320, 256, 0, stream>>>((unsigned*)slots, bsum, bar, b_ih, b_hh);
        kpack_w<<<50000, 256, 0, stream>>>(Ww, Wwf, 1250, 20, 0, 620, WORD, VOCAB, 0);
        kpack_w<<<17550, 256, 0, stream>>>(W_ih, Wbf, 117, 75, 0, 2400, XK, 1860, 1);
        kpack_w<<<1560, 256, 0, stream>>>(W_ih + (size_t)0 * XK,    Wgf3 + 0 * 798720, 39, 20, 2400, 620, XK, 620, 0);
        kpack_w<<<1560, 256, 0, stream>>>(W_ih + (size_t)1240 * XK, Wgf3 + 1 * 798720, 39, 20, 2400, 620, XK, 620, 0);
        kpack_w<<<1560, 256, 0, stream>>>(W_ih + (size_t)1860 * XK, Wgf3 + 2 * 798720, 39, 20, 2400, 620, XK, 620, 0);
        kpack_ctx<<<1200, 256, 0, stream>>>(thoughts, ctxf);
        kpack_embed<<<50000, 256, 0, stream>>>(embed, ehi, elo);
        ggemm<<<15, 256, 0, stream>>>(ctxf, Wbf, bsum, nullptr, base, 75, 117, 1872);

        kmega<<<NBLK, 512, 0, stream>>>(ehi, elo, Wgf3, Wwf, base, bw, hfrot, slots, out, bar);
    } else {
        // round-2 fallback layout
        const size_t F_WWF  = 0;
        const size_t F_WBF  = 51200000;
        const size_t F_WGF  = 69171200;
        const size_t F_CTXF = 73963520;
        const size_t F_HF   = 75192320;
        const size_t F_LF   = 75520000;
        const size_t F_BASE = 75847680;
        const size_t F_GATE = 76806144;
        const size_t F_BSUM = 77764608;
        const size_t F_SLOT = 77772096;

        unsigned short* Wwf  = (unsigned short*)(ws + F_WWF);
        unsigned short* Wbf  = (unsigned short*)(ws + F_WBF);
        unsigned short* Wgf  = (unsigned short*)(ws + F_WGF);
        unsigned short* ctxf = (unsigned short*)(ws + F_CTXF);
        unsigned short* hf   = (unsigned short*)(ws + F_HF);
        unsigned short* lf   = (unsigned short*)(ws + F_LF);
        float* base = (float*)(ws + F_BASE);
        float* gate = (float*)(ws + F_GATE);
        float* bsum = (float*)(ws + F_BSUM);
        u64*   slots = (u64*)(ws + F_SLOT);

        kinit2<<<320, 256, 0, stream>>>((unsigned int*)lf, (unsigned int*)hf,
                                        (unsigned int*)slots, bsum, b_ih, b_hh);
        kpack_w<<<50000, 256, 0, stream>>>(Ww, Wwf, 1250, 20, 0, 620, WORD, VOCAB, 0);
        kpack_w<<<17550, 256, 0, stream>>>(W_ih, Wbf, 117, 75, 0, 2400, XK, 1860, 1);
        kpack_w<<<4680, 256, 0, stream>>>(W_ih, Wgf, 117, 20, 2400, 620, XK, 1860, 1);
        kpack_ctx<<<1200, 256, 0, stream>>>(thoughts, ctxf);
        ggemm<<<15, 256, 0, stream>>>(ctxf, Wbf, bsum, nullptr, base, 75, 117, 1872);
        for (int t = 0; t < TMAX; ++t) {
            ggemm<<<15, 256, 0, stream>>>(lf, Wgf, nullptr, base, gate, 20, 117, 1872);
            kact<<<NSEQ, 640, 0, stream>>>(gate, hf);
            klogits2<<<157, 256, 0, stream>>>(hf, Wwf, bw, out, slots, t);
            if (t + 1 < TMAX)
                kgather2<<<NSEQ, 640, 0, stream>>>(embed, slots, lf, t);
        }
    }
}